// Round 1
// baseline (52.459 us; speedup 1.0000x reference)
//
#include <hip/hip_runtime.h>

// Logic gate belief-propagation forward, algebraically reduced:
//   Y[s, 2b+j] = P[0,2b+j] + P[1,2b+j]*x0 + P[2,2b+j]*x1 + P[3,2b+j]*x0*x1
// with x0 = X[s,2b], x1 = X[s,2b+1].
// (Hadamard corner table + multilinear hypercube interpolation cancel exactly.)
//
// Memory-bound: 128 MiB read (X) + 128 MiB write (Y); P (64 KiB) is hoisted
// into registers per thread (thread owns a fixed 4-column group, loops rows).

#define NUM_IN 4096
#define N_SLOW 8192

__global__ __launch_bounds__(256) void logic_poly_kernel(
    const float* __restrict__ X,
    const float* __restrict__ P,
    float* __restrict__ Y,
    int rows_per_chunk)
{
    // 4096 columns / 4 per float4 = 1024 column-groups per row.
    // blockIdx.x & 3 selects which 256-wide group tile; blockIdx.x >> 2 selects row chunk.
    const int col4 = (blockIdx.x & 3) * 256 + threadIdx.x;   // [0, 1024)
    const int c0   = col4 * 4;                               // even -> aligned to gate blocks

    // Loop-invariant coefficients for these 4 output columns (one per monomial).
    const float4 p0 = *reinterpret_cast<const float4*>(P + 0 * NUM_IN + c0);
    const float4 p1 = *reinterpret_cast<const float4*>(P + 1 * NUM_IN + c0);
    const float4 p2 = *reinterpret_cast<const float4*>(P + 2 * NUM_IN + c0);
    const float4 p3 = *reinterpret_cast<const float4*>(P + 3 * NUM_IN + c0);

    const int row_begin = (blockIdx.x >> 2) * rows_per_chunk;
    const int row_end   = min(row_begin + rows_per_chunk, N_SLOW);

    for (int s = row_begin; s < row_end; ++s) {
        const size_t off = (size_t)s * NUM_IN + c0;
        const float4 x = *reinterpret_cast<const float4*>(X + off);

        const float x01 = x.x * x.y;   // gate block 2t
        const float x23 = x.z * x.w;   // gate block 2t+1

        float4 y;
        y.x = p0.x + p1.x * x.x + p2.x * x.y + p3.x * x01;
        y.y = p0.y + p1.y * x.x + p2.y * x.y + p3.y * x01;
        y.z = p0.z + p1.z * x.z + p2.z * x.w + p3.z * x23;
        y.w = p0.w + p1.w * x.z + p2.w * x.w + p3.w * x23;

        *reinterpret_cast<float4*>(Y + off) = y;
    }
}

extern "C" void kernel_launch(void* const* d_in, const int* in_sizes, int n_in,
                              void* d_out, int out_size, void* d_ws, size_t ws_size,
                              hipStream_t stream) {
    const float* X = (const float*)d_in[0];   // (8192, 4096) f32
    const float* P = (const float*)d_in[1];   // (4, 4096) f32
    float* Y = (float*)d_out;                 // (8192, 4096) f32

    const int ROWS_PER_CHUNK = 32;            // 8192/32 = 256 row chunks
    const int n_chunks = (N_SLOW + ROWS_PER_CHUNK - 1) / ROWS_PER_CHUNK;
    dim3 grid(4 * n_chunks);                  // 1024 blocks
    dim3 block(256);
    logic_poly_kernel<<<grid, block, 0, stream>>>(X, P, Y, ROWS_PER_CHUNK);
}

// Round 3
// 44.193 us; speedup vs baseline: 1.1870x; 1.1870x over previous
//
#include <hip/hip_runtime.h>

// Logic gate belief-propagation forward, algebraically reduced:
//   Y[s, 2b+j] = P[0,2b+j] + P[1,2b+j]*x0 + P[2,2b+j]*x1 + P[3,2b+j]*x0*x1
// with x0 = X[s,2b], x1 = X[s,2b+1].
// (Hadamard corner table + multilinear hypercube interpolation cancel exactly.)
//
// Memory-bound. R2 = R1 with native ext_vector_type so
// __builtin_nontemporal_store compiles (HIP_vector_type is a struct -> rejected).
//  - grid 2048 blocks (rows_per_chunk 16): fill all 8192 wave slots.
//  - non-temporal Y stores (nt): keep X resident in the 256 MiB L3.
//  - unroll x2 with loads hoisted: 2 outstanding global_load_dwordx4 per wave.

#define NUM_IN 4096
#define N_SLOW 8192
#define ROWS_PER_CHUNK 16

typedef float f32x4 __attribute__((ext_vector_type(4)));

__global__ __launch_bounds__(256) void logic_poly_kernel(
    const float* __restrict__ X,
    const float* __restrict__ P,
    float* __restrict__ Y)
{
    // 4096 columns / 4 per float4 = 1024 column-groups per row.
    const int col4 = (blockIdx.x & 3) * 256 + threadIdx.x;   // [0, 1024)
    const int c0   = col4 * 4;                               // aligned to gate blocks

    // Loop-invariant coefficients for these 4 output columns (one per monomial).
    const f32x4 p0 = *reinterpret_cast<const f32x4*>(P + 0 * NUM_IN + c0);
    const f32x4 p1 = *reinterpret_cast<const f32x4*>(P + 1 * NUM_IN + c0);
    const f32x4 p2 = *reinterpret_cast<const f32x4*>(P + 2 * NUM_IN + c0);
    const f32x4 p3 = *reinterpret_cast<const f32x4*>(P + 3 * NUM_IN + c0);

    const int row_begin = (blockIdx.x >> 2) * ROWS_PER_CHUNK;

    #pragma unroll
    for (int u = 0; u < ROWS_PER_CHUNK / 2; ++u) {
        const int s0 = row_begin + 2 * u;
        const size_t offA = (size_t)s0 * NUM_IN + c0;
        const size_t offB = offA + NUM_IN;

        // Issue both loads before any compute: 2 outstanding dwordx4 per wave.
        const f32x4 xa = *reinterpret_cast<const f32x4*>(X + offA);
        const f32x4 xb = *reinterpret_cast<const f32x4*>(X + offB);

        f32x4 ya, yb;
        {
            const float m01 = xa.x * xa.y;
            const float m23 = xa.z * xa.w;
            ya.x = p0.x + p1.x * xa.x + p2.x * xa.y + p3.x * m01;
            ya.y = p0.y + p1.y * xa.x + p2.y * xa.y + p3.y * m01;
            ya.z = p0.z + p1.z * xa.z + p2.z * xa.w + p3.z * m23;
            ya.w = p0.w + p1.w * xa.z + p2.w * xa.w + p3.w * m23;
        }
        {
            const float m01 = xb.x * xb.y;
            const float m23 = xb.z * xb.w;
            yb.x = p0.x + p1.x * xb.x + p2.x * xb.y + p3.x * m01;
            yb.y = p0.y + p1.y * xb.x + p2.y * xb.y + p3.y * m01;
            yb.z = p0.z + p1.z * xb.z + p2.z * xb.w + p3.z * m23;
            yb.w = p0.w + p1.w * xb.z + p2.w * xb.w + p3.w * m23;
        }

        // Non-temporal: stream writes past L2/L3 so X stays cache-resident.
        __builtin_nontemporal_store(ya, reinterpret_cast<f32x4*>(Y + offA));
        __builtin_nontemporal_store(yb, reinterpret_cast<f32x4*>(Y + offB));
    }
}

extern "C" void kernel_launch(void* const* d_in, const int* in_sizes, int n_in,
                              void* d_out, int out_size, void* d_ws, size_t ws_size,
                              hipStream_t stream) {
    const float* X = (const float*)d_in[0];   // (8192, 4096) f32
    const float* P = (const float*)d_in[1];   // (4, 4096) f32
    float* Y = (float*)d_out;                 // (8192, 4096) f32

    const int n_chunks = N_SLOW / ROWS_PER_CHUNK;  // 512
    dim3 grid(4 * n_chunks);                       // 2048 blocks
    dim3 block(256);
    logic_poly_kernel<<<grid, block, 0, stream>>>(X, P, Y);
}

// Round 4
// 43.486 us; speedup vs baseline: 1.2063x; 1.0162x over previous
//
#include <hip/hip_runtime.h>

// Logic gate belief-propagation forward, algebraically reduced:
//   Y[s, 2b+j] = P[0,2b+j] + P[1,2b+j]*x0 + P[2,2b+j]*x1 + P[3,2b+j]*x0*x1
// with x0 = X[s,2b], x1 = X[s,2b+1].
//
// Memory-bound at ~197 MB/dispatch HBM traffic (67 MB X fetch after L3
// retention + 131 MB Y write; X+Y > 256 MiB L3 so ~50% X hit is a capacity
// fact). R3 change: unroll x4 -> 4 outstanding global_load_dwordx4 per wave
// to close the MLP gap vs the 6.3 TB/s copy ceiling.

#define NUM_IN 4096
#define N_SLOW 8192
#define ROWS_PER_CHUNK 16
#define UNROLL 4

typedef float f32x4 __attribute__((ext_vector_type(4)));

__global__ __launch_bounds__(256) void logic_poly_kernel(
    const float* __restrict__ X,
    const float* __restrict__ P,
    float* __restrict__ Y)
{
    // 4096 columns / 4 per float4 = 1024 column-groups per row.
    const int col4 = (blockIdx.x & 3) * 256 + threadIdx.x;   // [0, 1024)
    const int c0   = col4 * 4;                               // aligned to gate blocks

    // Loop-invariant coefficients for these 4 output columns (one per monomial).
    const f32x4 p0 = *reinterpret_cast<const f32x4*>(P + 0 * NUM_IN + c0);
    const f32x4 p1 = *reinterpret_cast<const f32x4*>(P + 1 * NUM_IN + c0);
    const f32x4 p2 = *reinterpret_cast<const f32x4*>(P + 2 * NUM_IN + c0);
    const f32x4 p3 = *reinterpret_cast<const f32x4*>(P + 3 * NUM_IN + c0);

    const int row_begin = (blockIdx.x >> 2) * ROWS_PER_CHUNK;

    #pragma unroll
    for (int u = 0; u < ROWS_PER_CHUNK / UNROLL; ++u) {
        const size_t off0 = (size_t)(row_begin + UNROLL * u) * NUM_IN + c0;

        // Issue all 4 loads before any compute: 4 outstanding dwordx4 per wave.
        f32x4 x[UNROLL];
        #pragma unroll
        for (int k = 0; k < UNROLL; ++k)
            x[k] = *reinterpret_cast<const f32x4*>(X + off0 + (size_t)k * NUM_IN);

        f32x4 y[UNROLL];
        #pragma unroll
        for (int k = 0; k < UNROLL; ++k) {
            const float m01 = x[k].x * x[k].y;
            const float m23 = x[k].z * x[k].w;
            y[k].x = p0.x + p1.x * x[k].x + p2.x * x[k].y + p3.x * m01;
            y[k].y = p0.y + p1.y * x[k].x + p2.y * x[k].y + p3.y * m01;
            y[k].z = p0.z + p1.z * x[k].z + p2.z * x[k].w + p3.z * m23;
            y[k].w = p0.w + p1.w * x[k].z + p2.w * x[k].w + p3.w * m23;
        }

        #pragma unroll
        for (int k = 0; k < UNROLL; ++k)
            __builtin_nontemporal_store(y[k],
                reinterpret_cast<f32x4*>(Y + off0 + (size_t)k * NUM_IN));
    }
}

extern "C" void kernel_launch(void* const* d_in, const int* in_sizes, int n_in,
                              void* d_out, int out_size, void* d_ws, size_t ws_size,
                              hipStream_t stream) {
    const float* X = (const float*)d_in[0];   // (8192, 4096) f32
    const float* P = (const float*)d_in[1];   // (4, 4096) f32
    float* Y = (float*)d_out;                 // (8192, 4096) f32

    const int n_chunks = N_SLOW / ROWS_PER_CHUNK;  // 512
    dim3 grid(4 * n_chunks);                       // 2048 blocks
    dim3 block(256);
    logic_poly_kernel<<<grid, block, 0, stream>>>(X, P, Y);
}

// Round 5
// 42.785 us; speedup vs baseline: 1.2261x; 1.0164x over previous
//
#include <hip/hip_runtime.h>

// Logic gate belief-propagation forward, algebraically reduced:
//   Y[s, 2b+j] = P[0,2b+j] + P[1,2b+j]*x0 + P[2,2b+j]*x1 + P[3,2b+j]*x0*x1
// with x0 = X[s,2b], x1 = X[s,2b+1].
//
// Memory-bound: ~197 MB/dispatch HBM (67 MB X after L3 retention + 131 MB Y).
// R5 changes vs R4 (43.5 us, 4.53 TB/s):
//  - software pipeline: issue iter u+1's 4 loads BEFORE compute/store of iter u
//    so the read stream stays in flight during the store burst (copy-bench style).
//  - ROWS_PER_CHUNK 16 -> 8 (grid 4096 = 16 blocks/CU): finer tail balance.

#define NUM_IN 4096
#define N_SLOW 8192
#define ROWS_PER_CHUNK 8
#define UNROLL 4
#define NITER (ROWS_PER_CHUNK / UNROLL)

typedef float f32x4 __attribute__((ext_vector_type(4)));

__global__ __launch_bounds__(256) void logic_poly_kernel(
    const float* __restrict__ X,
    const float* __restrict__ P,
    float* __restrict__ Y)
{
    // 4096 columns / 4 per float4 = 1024 column-groups per row.
    const int col4 = (blockIdx.x & 3) * 256 + threadIdx.x;   // [0, 1024)
    const int c0   = col4 * 4;                               // aligned to gate blocks

    // Loop-invariant coefficients for these 4 output columns (one per monomial).
    const f32x4 p0 = *reinterpret_cast<const f32x4*>(P + 0 * NUM_IN + c0);
    const f32x4 p1 = *reinterpret_cast<const f32x4*>(P + 1 * NUM_IN + c0);
    const f32x4 p2 = *reinterpret_cast<const f32x4*>(P + 2 * NUM_IN + c0);
    const f32x4 p3 = *reinterpret_cast<const f32x4*>(P + 3 * NUM_IN + c0);

    const int row_begin = (blockIdx.x >> 2) * ROWS_PER_CHUNK;
    const size_t base = (size_t)row_begin * NUM_IN + c0;

    // Prologue: loads for iteration 0.
    f32x4 x[UNROLL];
    #pragma unroll
    for (int k = 0; k < UNROLL; ++k)
        x[k] = *reinterpret_cast<const f32x4*>(X + base + (size_t)k * NUM_IN);

    #pragma unroll
    for (int u = 0; u < NITER; ++u) {
        const size_t off0 = base + (size_t)(UNROLL * u) * NUM_IN;

        // Prefetch next iteration's loads BEFORE compute/store of this one,
        // keeping the read stream in flight during the write burst.
        f32x4 xn[UNROLL];
        if (u + 1 < NITER) {
            const size_t offn = off0 + (size_t)UNROLL * NUM_IN;
            #pragma unroll
            for (int k = 0; k < UNROLL; ++k)
                xn[k] = *reinterpret_cast<const f32x4*>(X + offn + (size_t)k * NUM_IN);
        }

        #pragma unroll
        for (int k = 0; k < UNROLL; ++k) {
            const float m01 = x[k].x * x[k].y;
            const float m23 = x[k].z * x[k].w;
            f32x4 y;
            y.x = p0.x + p1.x * x[k].x + p2.x * x[k].y + p3.x * m01;
            y.y = p0.y + p1.y * x[k].x + p2.y * x[k].y + p3.y * m01;
            y.z = p0.z + p1.z * x[k].z + p2.z * x[k].w + p3.z * m23;
            y.w = p0.w + p1.w * x[k].z + p2.w * x[k].w + p3.w * m23;
            __builtin_nontemporal_store(y,
                reinterpret_cast<f32x4*>(Y + off0 + (size_t)k * NUM_IN));
        }

        if (u + 1 < NITER) {
            #pragma unroll
            for (int k = 0; k < UNROLL; ++k)
                x[k] = xn[k];
        }
    }
}

extern "C" void kernel_launch(void* const* d_in, const int* in_sizes, int n_in,
                              void* d_out, int out_size, void* d_ws, size_t ws_size,
                              hipStream_t stream) {
    const float* X = (const float*)d_in[0];   // (8192, 4096) f32
    const float* P = (const float*)d_in[1];   // (4, 4096) f32
    float* Y = (float*)d_out;                 // (8192, 4096) f32

    const int n_chunks = N_SLOW / ROWS_PER_CHUNK;  // 1024
    dim3 grid(4 * n_chunks);                       // 4096 blocks
    dim3 block(256);
    logic_poly_kernel<<<grid, block, 0, stream>>>(X, P, Y);
}